// Round 6
// baseline (13808.342 us; speedup 1.0000x reference)
//
#include <hip/hip_runtime.h>
#include <hip/hip_bf16.h>
#include <math.h>

#define T_STEPS 1024
#define HDIM    2048
#define ADIM    64
#define NBLK    256
#define NTHR    512
#define WPB     8            // waves/block = rows/block

typedef unsigned int u32;
typedef unsigned int uint4v __attribute__((ext_vector_type(4)));

// Dynamic LDS layout (bytes):
//   [0,131072)        : 4 weight sets (W_r,W_z,W_n,fc1), bf16x2, 8 rows x 1024 u32 each
//   [131072,151552)   : fc2 partial k<1280, 8 rows x 640 u32
//   [151552,159744)   : lsv, 2048 fp32 staging vector
#define SMEM_BYTES 159744
#define FC2_U32    32768
#define LSV_BYTES  151552

__device__ __forceinline__ float elu_f(float x)      { return x > 0.f ? x : expm1f(x); }
__device__ __forceinline__ float sigmoid_f(float x)  { return 1.f / (1.f + expf(-x)); }
__device__ __forceinline__ float softplus_f(float x) { return x > 0.f ? x + log1pf(expf(-x)) : log1pf(expf(x)); }

__device__ __forceinline__ u32 bf16rne(float x) {
    u32 u = __float_as_uint(x);
    return (u + 0x7fffu + ((u >> 16) & 1u)) >> 16;
}
__device__ __forceinline__ u32 pack_bf16(float lo, float hi) {
    return bf16rne(lo) | (bf16rne(hi) << 16);
}
__device__ __forceinline__ float blo(u32 u) { return __uint_as_float(u << 16); }
__device__ __forceinline__ float bhi(u32 u) { return __uint_as_float(u & 0xffff0000u); }

// Producer store: tag (hi32) + fp32 payload (lo32) published by ONE 8B
// device-coherent atomic store -> data is its own ready flag.
__device__ __forceinline__ void cstore64(unsigned long long* p, u32 tag, float v) {
    unsigned long long x = ((unsigned long long)tag << 32) | (unsigned long long)__float_as_uint(v);
    __hip_atomic_store(p, x, __ATOMIC_RELAXED, __HIP_MEMORY_SCOPE_AGENT);
}

// 16B cache-bypass loads: 2 tagged slots per fabric transaction (vs 1 for the
// 8B atomic-load path) -> halves poll congestion at the coherence point.
__device__ __forceinline__ void bypass_load2(uint4v& a, uint4v& b,
                                             const unsigned long long* pa,
                                             const unsigned long long* pb) {
    asm volatile("global_load_dwordx4 %0, %2, off sc0 sc1\n\t"
                 "global_load_dwordx4 %1, %3, off sc0 sc1\n\t"
                 "s_waitcnt vmcnt(0)"
                 : "=v"(a), "=v"(b)
                 : "v"(pa), "v"(pb));
}

// Poll all 2048 tagged slots for `tag`; stash payloads into lsv.
// Thread i owns slot pairs {2i,2i+1} and {1024+2i,1024+2i+1}.
// Entry barrier protects lsv readers of the previous stage; exit barrier
// publishes the fully staged vector block-wide.
__device__ __forceinline__ void consume_vec(const unsigned long long* __restrict__ tg,
                                            u32 tag, float* __restrict__ lsv) {
    __syncthreads();
    const int i = threadIdx.x;
    const unsigned long long* pa = tg + 2 * i;
    const unsigned long long* pb = tg + 1024 + 2 * i;
    uint4v a, b;
    bypass_load2(a, b, pa, pb);
    u32 pend = 0xFu;
    for (;;) {
        if ((pend & 1u) && a.y == tag) { lsv[2*i]        = __uint_as_float(a.x); pend &= ~1u; }
        if ((pend & 2u) && a.w == tag) { lsv[2*i+1]      = __uint_as_float(a.z); pend &= ~2u; }
        if ((pend & 4u) && b.y == tag) { lsv[1024+2*i]   = __uint_as_float(b.x); pend &= ~4u; }
        if ((pend & 8u) && b.w == tag) { lsv[1025+2*i]   = __uint_as_float(b.z); pend &= ~8u; }
        if (!pend) break;
        if (pend & 3u)
            asm volatile("global_load_dwordx4 %0, %1, off sc0 sc1" : "=v"(a) : "v"(pa));
        if (pend & 12u)
            asm volatile("global_load_dwordx4 %0, %1, off sc0 sc1" : "=v"(b) : "v"(pb));
        asm volatile("s_waitcnt vmcnt(0)");
    }
    __syncthreads();
}

// 8-element bf16-row x fp32-lsv dot fragment (one uint4v = 8 weights)
#define DOT8(acc, wv, s0, s1)                                                  \
    acc += blo(wv.x)*s0.x + bhi(wv.x)*s0.y + blo(wv.y)*s0.z + bhi(wv.y)*s0.w   \
         + blo(wv.z)*s1.x + bhi(wv.z)*s1.y + blo(wv.w)*s1.z + bhi(wv.w)*s1.w

// ---------------------------------------------------------------------------
// Persistent sequential kernel. Weights live in LDS (bf16) — guaranteed
// resident, no register-allocator games. Wave w owns row j = blk*8 + w.
// ---------------------------------------------------------------------------
__global__ void __launch_bounds__(NTHR, 1) gru_seq_kernel(
    const float* __restrict__ actions, const float* __restrict__ state,
    const float* __restrict__ W_ih, const float* __restrict__ W_hh,
    const float* __restrict__ b_ih, const float* __restrict__ b_hh,
    const float* __restrict__ fc1_w, const float* __restrict__ fc1_b,
    const float* __restrict__ fc2_w, const float* __restrict__ fc2_b,
    float* __restrict__ s_all,
    unsigned long long* __restrict__ tg0,
    unsigned long long* __restrict__ tg1,
    unsigned long long* __restrict__ tg2)
{
    extern __shared__ __align__(16) unsigned char smem[];
    u32*   lwu = (u32*)smem;
    float* lsv = (float*)(smem + LSV_BYTES);
    const float4* ls4 = (const float4*)lsv;

    const int tid  = threadIdx.x;
    const int lane = tid & 63;
    const int wave = tid >> 6;
    const int j    = blockIdx.x * WPB + wave;   // 0..2047

    // --- prologue: weights -> LDS as bf16x2 ---
    for (int g = 0; g < 4; ++g) {
        const float* basep = (g < 3) ? (W_hh + ((size_t)g * HDIM + (size_t)blockIdx.x * WPB) * HDIM)
                                     : (fc1_w + (size_t)blockIdx.x * WPB * HDIM);
        for (int p = tid; p < 8192; p += NTHR) {
            const int r = p >> 10, cu = p & 1023;
            const float2 v = *(const float2*)&basep[(size_t)r * HDIM + 2 * cu];
            lwu[g * 8192 + p] = pack_bf16(v.x, v.y);
        }
    }
    for (int p = tid; p < 5120; p += NTHR) {
        const int r = p / 640, cu = p % 640;
        const float2 v = *(const float2*)&fc2_w[((size_t)blockIdx.x * WPB + r) * HDIM + 2 * cu];
        lwu[FC2_U32 + p] = pack_bf16(v.x, v.y);
    }
    // fc2 tail (k in [1280,2048)) stays fp32 in 12 registers/lane
    float f2t[12];
    #pragma unroll
    for (int c = 0; c < 12; ++c)
        f2t[c] = fc2_w[(size_t)j * HDIM + 1280 + c * 64 + lane];

    const float wih_r = W_ih[(size_t)j * ADIM + lane];
    const float wih_z = W_ih[(size_t)(HDIM + j) * ADIM + lane];
    const float wih_n = W_ih[(size_t)(2 * HDIM + j) * ADIM + lane];
    const float bias_r = b_ih[j] + b_hh[j];
    const float bias_z = b_ih[HDIM + j] + b_hh[HDIM + j];
    const float bihn   = b_ih[2 * HDIM + j];
    const float bhhn   = b_hh[2 * HDIM + j];
    const float fb1    = fc1_b[j];
    const float fb2    = fc2_b[j];
    __syncthreads();   // weight LDS fill complete

    const u32* rowR = lwu + 0 * 8192 + wave * 1024;
    const u32* rowZ = lwu + 1 * 8192 + wave * 1024;
    const u32* rowN = lwu + 2 * 8192 + wave * 1024;
    const u32* row1 = lwu + 3 * 8192 + wave * 1024;
    const u32* row2 = lwu + FC2_U32 + wave * 640;

    for (int t = 0; t < T_STEPS; ++t) {
        const u32 base = 3u * (u32)t;
        const float av = actions[t * ADIM + lane];

        // ================= stage 1: GRU cell =================
        if (t == 0) {
            #pragma unroll
            for (int q = 0; q < 4; ++q)
                lsv[tid + q * NTHR] = state[tid + q * NTHR];
            __syncthreads();
        } else {
            consume_vec(tg2, base, lsv);   // s_{t-1}
        }
        {
            float dr = 0.f, dz = 0.f, dnH = 0.f;
            #pragma unroll
            for (int i = 0; i < 4; ++i) {
                const int ui = i * 256 + lane * 4;
                const uint4v wa = *(const uint4v*)&rowR[ui];
                const uint4v wb = *(const uint4v*)&rowZ[ui];
                const uint4v wc = *(const uint4v*)&rowN[ui];
                const float4 s0 = ls4[i * 128 + lane * 2];
                const float4 s1 = ls4[i * 128 + lane * 2 + 1];
                DOT8(dr, wa, s0, s1);
                DOT8(dz, wb, s0, s1);
                DOT8(dnH, wc, s0, s1);
            }
            float dnA = av * wih_n;
            dr += av * wih_r;
            dz += av * wih_z;
            #pragma unroll
            for (int m = 32; m > 0; m >>= 1) {
                dr  += __shfl_xor(dr, m, 64);
                dz  += __shfl_xor(dz, m, 64);
                dnH += __shfl_xor(dnH, m, 64);
                dnA += __shfl_xor(dnA, m, 64);
            }
            if (lane == 0) {
                const float r  = sigmoid_f(dr + bias_r);
                const float z  = sigmoid_f(dz + bias_z);
                const float n  = tanhf(dnA + bihn + r * (dnH + bhhn));
                const float hp = lsv[j];
                const float hn = (1.f - z) * n + z * hp;
                cstore64(&tg0[j], base + 1u, elu_f(hn));
            }
        }

        // ================= stage 2: fc1 =================
        consume_vec(tg0, base + 1u, lsv);
        {
            float d1 = 0.f;
            #pragma unroll
            for (int i = 0; i < 4; ++i) {
                const int ui = i * 256 + lane * 4;
                const uint4v wv = *(const uint4v*)&row1[ui];
                const float4 s0 = ls4[i * 128 + lane * 2];
                const float4 s1 = ls4[i * 128 + lane * 2 + 1];
                DOT8(d1, wv, s0, s1);
            }
            #pragma unroll
            for (int m = 32; m > 0; m >>= 1) d1 += __shfl_xor(d1, m, 64);
            if (lane == 0) cstore64(&tg1[j], base + 2u, elu_f(d1 + fb1));
        }

        // ================= stage 3: fc2 -> s_t =================
        consume_vec(tg1, base + 2u, lsv);
        {
            float d2 = 0.f;
            #pragma unroll
            for (int i = 0; i < 2; ++i) {        // k in [0,1024)
                const int ui = i * 256 + lane * 4;
                const uint4v wv = *(const uint4v*)&row2[ui];
                const float4 s0 = ls4[i * 128 + lane * 2];
                const float4 s1 = ls4[i * 128 + lane * 2 + 1];
                DOT8(d2, wv, s0, s1);
            }
            {                                     // k in [1024,1280)
                const uint2 wv = *(const uint2*)&row2[512 + lane * 2];
                const float4 s0 = ls4[256 + lane];
                d2 += blo(wv.x)*s0.x + bhi(wv.x)*s0.y + blo(wv.y)*s0.z + bhi(wv.y)*s0.w;
            }
            #pragma unroll
            for (int c = 0; c < 12; ++c)          // k in [1280,2048), fp32 regs
                d2 += f2t[c] * lsv[1280 + c * 64 + lane];
            #pragma unroll
            for (int m = 32; m > 0; m >>= 1) d2 += __shfl_xor(d2, m, 64);
            if (lane == 0) {
                const float v = elu_f(d2 + fb2);
                cstore64(&tg2[j], base + 3u, v);
                s_all[(size_t)t * HDIM + j] = v;   // plain store; read after kernel end
            }
        }
    }
}

// ---------------------------------------------------------------------------
// Head GEMM (unchanged): C[t, n], n<2048 -> mean, else softplus(std).
// ---------------------------------------------------------------------------
__global__ void __launch_bounds__(256) head_gemm_kernel(
    const float* __restrict__ s_all,
    const float* __restrict__ mean_w, const float* __restrict__ mean_b,
    const float* __restrict__ std_w,  const float* __restrict__ std_b,
    float* __restrict__ out)
{
    __shared__ float As[32 * 64];
    __shared__ float Bs[32 * 64];

    const int n0 = blockIdx.x * 64;
    const int t0 = blockIdx.y * 64;
    const bool is_std = (n0 >= HDIM);
    const float* W    = is_std ? std_w : mean_w;
    const float* bias = is_std ? std_b : mean_b;
    const int j0 = is_std ? (n0 - HDIM) : n0;

    const int tid = threadIdx.x;
    const int tx = tid & 15;
    const int ty = tid >> 4;

    float acc[4][4] = {};

    for (int k0 = 0; k0 < HDIM; k0 += 32) {
        __syncthreads();
        #pragma unroll
        for (int p = 0; p < 2; ++p) {
            const int id = tid + p * 256;
            const int m  = id >> 3;
            const int kk = id & 7;
            const float4 a = *(const float4*)&s_all[(size_t)(t0 + m) * HDIM + k0 + kk * 4];
            As[(kk * 4 + 0) * 64 + m] = a.x;
            As[(kk * 4 + 1) * 64 + m] = a.y;
            As[(kk * 4 + 2) * 64 + m] = a.z;
            As[(kk * 4 + 3) * 64 + m] = a.w;
            const float4 b = *(const float4*)&W[(size_t)(j0 + m) * HDIM + k0 + kk * 4];
            Bs[(kk * 4 + 0) * 64 + m] = b.x;
            Bs[(kk * 4 + 1) * 64 + m] = b.y;
            Bs[(kk * 4 + 2) * 64 + m] = b.z;
            Bs[(kk * 4 + 3) * 64 + m] = b.w;
        }
        __syncthreads();

        #pragma unroll
        for (int k = 0; k < 32; ++k) {
            const float4 a = *(const float4*)&As[k * 64 + ty * 4];
            const float4 b = *(const float4*)&Bs[k * 64 + tx * 4];
            const float am[4] = {a.x, a.y, a.z, a.w};
            const float bn[4] = {b.x, b.y, b.z, b.w};
            #pragma unroll
            for (int i = 0; i < 4; ++i)
                #pragma unroll
                for (int jj = 0; jj < 4; ++jj)
                    acc[i][jj] += am[i] * bn[jj];
        }
    }

    const size_t off = is_std ? (size_t)T_STEPS * HDIM : 0;
    #pragma unroll
    for (int i = 0; i < 4; ++i) {
        const int tt = t0 + ty * 4 + i;
        const int jc = j0 + tx * 4;
        float4 v;
        float* vp = (float*)&v;
        #pragma unroll
        for (int jj = 0; jj < 4; ++jj) {
            float val = acc[i][jj] + bias[jc + jj];
            if (is_std) val = softplus_f(val);
            vp[jj] = val;
        }
        *(float4*)&out[off + (size_t)tt * HDIM + jc] = v;
    }
}

// ---------------------------------------------------------------------------
extern "C" void kernel_launch(void* const* d_in, const int* in_sizes, int n_in,
                              void* d_out, int out_size, void* d_ws, size_t ws_size,
                              hipStream_t stream) {
    (void)in_sizes; (void)n_in; (void)out_size; (void)ws_size;
    const float* actions = (const float*)d_in[0];
    const float* state   = (const float*)d_in[1];
    const float* W_ih    = (const float*)d_in[2];
    const float* W_hh    = (const float*)d_in[3];
    const float* b_ih    = (const float*)d_in[4];
    const float* b_hh    = (const float*)d_in[5];
    const float* fc1_w   = (const float*)d_in[6];
    const float* fc1_b   = (const float*)d_in[7];
    const float* fc2_w   = (const float*)d_in[8];
    const float* fc2_b   = (const float*)d_in[9];
    const float* mean_w  = (const float*)d_in[10];
    const float* mean_b  = (const float*)d_in[11];
    const float* std_w   = (const float*)d_in[12];
    const float* std_b   = (const float*)d_in[13];
    float* out = (float*)d_out;

    float* s_all = (float*)d_ws;                              // [T, H] fp32
    unsigned long long* tg0 = (unsigned long long*)(s_all + (size_t)T_STEPS * HDIM);
    unsigned long long* tg1 = tg0 + HDIM;
    unsigned long long* tg2 = tg1 + HDIM;
    // no memset needed: 0xAA poison never matches a ticket (1..3072)

    // allow >64KB dynamic LDS (idempotent; ignore result)
    (void)hipFuncSetAttribute((const void*)gru_seq_kernel,
                              hipFuncAttributeMaxDynamicSharedMemorySize, SMEM_BYTES);

    void* args[] = { &actions, &state, &W_ih, &W_hh, &b_ih, &b_hh,
                     &fc1_w, &fc1_b, &fc2_w, &fc2_b,
                     &s_all, &tg0, &tg1, &tg2 };
    hipLaunchCooperativeKernel((const void*)gru_seq_kernel,
                               dim3(NBLK), dim3(NTHR), args, SMEM_BYTES, stream);

    dim3 grid(4096 / 64, T_STEPS / 64);
    head_gemm_kernel<<<grid, 256, 0, stream>>>(s_all, mean_w, mean_b, std_w, std_b, out);
}